// Round 9
// baseline (1026.273 us; speedup 1.0000x reference)
//
#include <hip/hip_runtime.h>

// MyCrossAttention fused kernel for MI355X (gfx950), round 9.
// B=4, C=128, T=400, F=64, H=4, HID=CV=32, N=B*T=1600.
// vs round 8 (passing, 351us): PERSISTENT blocks — grid=512 (exactly 2 blocks/CU),
// each block grid-strides over 3-4 tokens. Weights/GZ stay L2-hot across a block's
// iterations; no dispatch-tail raggedness. Next token's x is prefetched into
// registers during phase 6 and written to LDS in phase 7 (issue-early/write-late).
// Per-token arithmetic is byte-identical to round 8.

typedef short s8v __attribute__((ext_vector_type(8)));   // 8 bf16 bits
typedef float f4v __attribute__((ext_vector_type(4)));   // MFMA accumulator / 16-B vector
typedef float fv4 __attribute__((ext_vector_type(4)));   // for nontemporal ld/st

__device__ __forceinline__ unsigned short f2bf(float x){
  unsigned u = __float_as_uint(x);
  return (unsigned short)((u + 0x7FFFu + ((u >> 16) & 1u)) >> 16);  // RNE
}
__device__ __forceinline__ float b2f(unsigned short b){
  return __uint_as_float(((unsigned)b) << 16);
}
__device__ __forceinline__ float wred(float v){
  #pragma unroll
  for (int off = 32; off; off >>= 1) v += __shfl_xor(v, off, 64);
  return v;
}

// ---------------- prep: W -> (hi, lo) bf16 pair; (g,z) packed bf16 [r][f] ----------------
// ws layout: Wb_hi 4x16384 shorts | Wb_lo 4x16384 shorts | GZ 4x8192 u32
__global__ __launch_bounds__(256)
void prep_k(const float* __restrict__ Wq, const float* __restrict__ Wk,
            const float* __restrict__ Wv, const float* __restrict__ Wo,
            const float* __restrict__ gq, const float* __restrict__ zq,
            const float* __restrict__ gk, const float* __restrict__ zk,
            const float* __restrict__ gv, const float* __restrict__ zv,
            const float* __restrict__ go, const float* __restrict__ zo,
            unsigned short* __restrict__ Wb, unsigned* __restrict__ GZ)
{
  int t = blockIdx.x * 256 + threadIdx.x;
  if (t < 65536) {                       // 4 x [128][128] weight matrices
    int sel = t >> 14, i = t & 16383;
    const float* s = sel == 0 ? Wq : sel == 1 ? Wk : sel == 2 ? Wv : Wo;
    float w = s[i];
    unsigned short hi = f2bf(w);
    Wb[t]         = hi;
    Wb[65536 + t] = f2bf(w - b2f(hi));   // lo residue
  } else {                               // 4 x [128][64] packed (g,z)
    int u = t - 65536;
    int sel = u >> 13, i = u & 8191;
    const float* g = sel == 0 ? gq : sel == 1 ? gk : sel == 2 ? gv : go;
    const float* z = sel == 0 ? zq : sel == 1 ? zk : sel == 2 ? zv : zo;
    GZ[u] = (unsigned)f2bf(g[i]) | ((unsigned)f2bf(z[i]) << 16);
  }
}

// ---------------- 32x64x128 GEMM tile: acc = (A_hi + A_lo) * B(LDS swizzled) ----------------
__device__ __forceinline__ void gemm_tile(const unsigned short* __restrict__ A,  // hi; lo at +65536
                                          const unsigned short* __restrict__ Bl,
                                          int m0, int n0, int row16, int q4,
                                          f4v acc[2][4])
{
  const unsigned short* Al = A + 65536;
  #pragma unroll
  for (int mi = 0; mi < 2; ++mi)
    #pragma unroll
    for (int ni = 0; ni < 4; ++ni)
      acc[mi][ni] = (f4v){0.f, 0.f, 0.f, 0.f};

  #pragma unroll
  for (int kk = 0; kk < 4; ++kk) {
    s8v ah[2], al[2];
    #pragma unroll
    for (int mi = 0; mi < 2; ++mi) {
      int off = (m0 + mi*16 + row16)*128 + kk*32 + q4*8;
      ah[mi] = *(const s8v*)(A  + off);
      al[mi] = *(const s8v*)(Al + off);
    }
    #pragma unroll
    for (int ni = 0; ni < 4; ++ni) {
      int rw = n0 + ni*16 + row16;
      const s8v b = *(const s8v*)(Bl + rw*128 + ((kk*32 + q4*8) ^ ((rw & 7) << 3)));
      #pragma unroll
      for (int mi = 0; mi < 2; ++mi) {
        acc[mi][ni] = __builtin_amdgcn_mfma_f32_16x16x32_bf16(ah[mi], b, acc[mi][ni], 0, 0, 0);
        acc[mi][ni] = __builtin_amdgcn_mfma_f32_16x16x32_bf16(al[mi], b, acc[mi][ni], 0, 0, 0);
      }
    }
  }
}

// ---------------- QKV epilogue: bias + PReLU + LN(2048 = wave tile) + g/z (scalar) ----------------
__device__ __forceinline__ void qkv_epi(f4v acc[2][4],
                                        const float* __restrict__ bias,
                                        float p,
                                        const unsigned* __restrict__ GZb,  // [r][f]
                                        unsigned short* __restrict__ Lout, bool keep,
                                        int m0, int n0, int row16, int q4)
{
  float sum = 0.f, sq = 0.f;
  #pragma unroll
  for (int mi = 0; mi < 2; ++mi) {
    #pragma unroll
    for (int j = 0; j < 4; ++j) {
      float bb = bias[m0 + mi*16 + q4*4 + j];
      #pragma unroll
      for (int ni = 0; ni < 4; ++ni) {
        float v = acc[mi][ni][j] + bb;
        v = v >= 0.f ? v : p * v;
        acc[mi][ni][j] = v;
        sum += v; sq += v*v;
      }
    }
  }
  sum = wred(sum); sq = wred(sq);
  float mu = sum * (1.f/2048.f);
  float rs = rsqrtf(sq * (1.f/2048.f) - mu*mu + 1e-5f);
  #pragma unroll
  for (int mi = 0; mi < 2; ++mi) {
    #pragma unroll
    for (int ni = 0; ni < 4; ++ni) {
      int f   = ni*16 + row16;
      int col = n0 + f;
      int sw  = (col & 7) << 3;
      #pragma unroll
      for (int j = 0; j < 4; ++j) {
        int r = m0 + mi*16 + q4*4 + j;
        unsigned gz = GZb[r*64 + f];
        float g = b2f((unsigned short)(gz & 0xffffu));
        float z = b2f((unsigned short)(gz >> 16));
        float vn = (acc[mi][ni][j] - mu) * rs * g + z;
        if (keep) acc[mi][ni][j] = vn;
        else      Lout[col*128 + (r ^ sw)] = f2bf(vn);
      }
    }
  }
}

// ---------------- main fused kernel (persistent) ----------------
__global__ __launch_bounds__(512) __attribute__((amdgpu_waves_per_eu(4, 4)))
void fused_k(const float* __restrict__ x1, const float* __restrict__ x2,
             const unsigned short* __restrict__ Wb, const unsigned* __restrict__ GZ,
             const float* __restrict__ bq, const float* __restrict__ bk,
             const float* __restrict__ bv, const float* __restrict__ bo,
             const float* __restrict__ pq, const float* __restrict__ pk,
             const float* __restrict__ pv, const float* __restrict__ po,
             float* __restrict__ out)
{
  __shared__ __align__(16) unsigned short Xl[16384];  // x, [rw=s*64+f][c], swizzled
  __shared__ __align__(16) unsigned short Kl[16384];  // K -> V -> mix -> f32 y stage
  __shared__ float sc[16];              // raw scores [h][s][t]
  __shared__ float lnb[16];             // out-LN cross-wave partials

  const int tid = threadIdx.x;
  const int lane = tid & 63, wave = tid >> 6;
  const int wm = wave >> 1, wn = wave & 1;     // wm = head (rows), wn = stream (cols)
  const int m0 = wm * 32, n0 = wn * 64;
  const int row16 = lane & 15, q4 = lane >> 4;
  const int stride = gridDim.x;

  // x-loader lane mapping (same for prologue and prefetch)
  const int pc = tid & 127, ps = (tid >> 7) & 1, ph = tid >> 8;

  int n = blockIdx.x;

  // ---- prologue: load x(n) -> Xl (bf16, transposed, swizzled) ----
  {
    const float* src = (ps ? x2 : x1) + ((size_t)((n/400)*128 + pc)*400 + (n%400))*64 + ph*32;
    #pragma unroll
    for (int j = 0; j < 8; ++j) {
      fv4 v = __builtin_nontemporal_load(((const fv4*)src) + j);
      int f0 = ph*32 + j*4;
      #pragma unroll
      for (int e = 0; e < 4; ++e) {
        int rw = ps*64 + f0 + e;
        Xl[rw*128 + (pc ^ ((rw & 7) << 3))] = f2bf(v[e]);
      }
    }
  }
  __syncthreads();

  while (n < 1600) {
    const int bI = n / 400, tI = n % 400;
    f4v acc[2][4];

    // ---- phase 2: K branch -> Kl (bf16) ----
    gemm_tile(Wb + 16384*1, Xl, m0, n0, row16, q4, acc);
    qkv_epi(acc, bk, pk[wm], GZ + 8192*1, Kl, false, m0, n0, row16, q4);
    __syncthreads();

    // ---- phase 3: Q branch (kept in regs fp32) + scores ----
    gemm_tile(Wb + 16384*0, Xl, m0, n0, row16, q4, acc);
    qkv_epi(acc, bq, pq[wm], GZ + 8192*0, Kl, true, m0, n0, row16, q4);
    {
      float p0 = 0.f, p1 = 0.f;   // scores vs K stream t=0,1 for (h=wm, s=wn)
      #pragma unroll
      for (int mi = 0; mi < 2; ++mi) {
        #pragma unroll
        for (int ni = 0; ni < 4; ++ni) {
          int f  = ni*16 + row16;
          int sw = (f & 7) << 3;      // (64+f)&7 == f&7
          #pragma unroll
          for (int j = 0; j < 4; ++j) {
            int r = m0 + mi*16 + q4*4 + j;
            float qv = acc[mi][ni][j];
            float k0 = b2f(Kl[f*128      + (r ^ sw)]);
            float k1 = b2f(Kl[(64+f)*128 + (r ^ sw)]);
            p0 += qv * k0;
            p1 += qv * k1;
          }
        }
      }
      p0 = wred(p0); p1 = wred(p1);
      if (lane == 0) {
        sc[wm*4 + wn*2 + 0] = p0;
        sc[wm*4 + wn*2 + 1] = p1;
      }
    }
    __syncthreads();   // score reads of Kl done; Kl reusable

    // ---- phase 4: V branch -> Kl (bf16) ----
    gemm_tile(Wb + 16384*2, Xl, m0, n0, row16, q4, acc);
    qkv_epi(acc, bv, pv[wm], GZ + 8192*2, Kl, false, m0, n0, row16, q4);
    __syncthreads();

    // ---- phase 5: softmax + 2x2 attention mix, in place in Kl (all 512 threads) ----
    {
      const float is = 0.02209708691f;  // 1/sqrt(2048)
      #pragma unroll
      for (int i = 0; i < 2; ++i) {
        int g  = tid + 512*i;           // 1024 groups: [f in 64][cgroup in 16]
        int f  = g >> 4, cg = g & 15, c0 = cg*8, h = cg >> 2;
        float s00 = sc[h*4+0]*is, s01 = sc[h*4+1]*is;
        float s10 = sc[h*4+2]*is, s11 = sc[h*4+3]*is;
        float mA = fmaxf(s00, s01), e0 = __expf(s00-mA), e1 = __expf(s01-mA);
        float a00 = e0/(e0+e1), a01 = e1/(e0+e1);
        float mB = fmaxf(s10, s11), e2 = __expf(s10-mB), e3 = __expf(s11-mB);
        float a10 = e2/(e2+e3), a11 = e3/(e2+e3);
        int sw = (f & 7) << 3;
        int off0 = f*128      + (c0 ^ sw);
        int off1 = (64+f)*128 + (c0 ^ sw);
        s8v v0 = *(const s8v*)(Kl + off0);
        s8v v1 = *(const s8v*)(Kl + off1);
        s8v o0, o1;
        #pragma unroll
        for (int e = 0; e < 8; ++e) {
          float x0  = b2f((unsigned short)v0[e]);
          float x1v = b2f((unsigned short)v1[e]);
          o0[e] = (short)f2bf(a00*x0 + a01*x1v);
          o1[e] = (short)f2bf(a10*x0 + a11*x1v);
        }
        *(s8v*)(Kl + off0) = o0;
        *(s8v*)(Kl + off1) = o1;
      }
    }
    __syncthreads();

    // ---- prefetch next token's x into registers (latency hidden under phase 6) ----
    const int nn = n + stride;
    const bool hn = nn < 1600;
    fv4 xr[8];
    if (hn) {
      const float* src = (ps ? x2 : x1) + ((size_t)((nn/400)*128 + pc)*400 + (nn%400))*64 + ph*32;
      #pragma unroll
      for (int j = 0; j < 8; ++j)
        xr[j] = __builtin_nontemporal_load(((const fv4*)src) + j);
    }

    // ---- phase 6: output projection + LN(8192 per stream) + g/z + residual ----
    gemm_tile(Wb + 16384*3, Kl, m0, n0, row16, q4, acc);
    {
      float pov = po[0];
      float sum = 0.f, sq = 0.f;
      #pragma unroll
      for (int mi = 0; mi < 2; ++mi) {
        #pragma unroll
        for (int j = 0; j < 4; ++j) {
          float bb = bo[m0 + mi*16 + q4*4 + j];
          #pragma unroll
          for (int ni = 0; ni < 4; ++ni) {
            float v = acc[mi][ni][j] + bb;
            v = v >= 0.f ? v : pov * v;
            acc[mi][ni][j] = v;
            sum += v; sq += v*v;
          }
        }
      }
      sum = wred(sum); sq = wred(sq);
      if (lane == 0) { lnb[wave] = sum; lnb[8 + wave] = sq; }
      __syncthreads();   // also: all phase-6 gemm reads of Kl complete
      float tot  = lnb[wn]   + lnb[wn+2]   + lnb[wn+4]   + lnb[wn+6];
      float totq = lnb[8+wn] + lnb[8+wn+2] + lnb[8+wn+4] + lnb[8+wn+6];
      float mu = tot * (1.f/8192.f);
      float rs = rsqrtf(totq * (1.f/8192.f) - mu*mu + 1e-5f);
      const unsigned* GZo = GZ + 8192*3;
      #pragma unroll
      for (int mi = 0; mi < 2; ++mi) {
        #pragma unroll
        for (int ni = 0; ni < 4; ++ni) {
          int f   = ni*16 + row16;
          int col = n0 + f;
          int sw  = (col & 7) << 3;
          #pragma unroll
          for (int j = 0; j < 4; ++j) {
            int r = m0 + mi*16 + q4*4 + j;
            unsigned gz = GZo[r*64 + f];
            float g = b2f((unsigned short)(gz & 0xffffu));
            float z = b2f((unsigned short)(gz >> 16));
            float y  = (acc[mi][ni][j] - mu) * rs * g + z;
            float xv = b2f(Xl[col*128 + (r ^ sw)]);   // residual (bf16-rounded x)
            acc[mi][ni][j] = y + xv;
          }
        }
      }
    }

    // ---- phase 7: stage y through LDS; coalesced nt stores; rewrite Xl for next n ----
    {
      float* KlF = (float*)Kl;   // 8192 floats = one stream's [r=128][f=64] tile
      const size_t obase = ((size_t)bI * 128 * 400 + (size_t)tI) * 64;

      // stream 0
      if (wn == 0) {
        #pragma unroll
        for (int mi = 0; mi < 2; ++mi)
          #pragma unroll
          for (int ni = 0; ni < 4; ++ni) {
            int f = ni*16 + row16;
            #pragma unroll
            for (int j = 0; j < 4; ++j)
              KlF[(m0 + mi*16 + q4*4 + j)*64 + f] = acc[mi][ni][j];
          }
      }
      __syncthreads();           // KlF(s0) ready; ALL Xl reads (residual) done
      {
        float* outs = out + obase;
        #pragma unroll
        for (int k = 0; k < 4; ++k) {
          int s = k*512 + tid;
          int r = s >> 4, f4 = (s & 15) * 4;
          fv4 v = *(const fv4*)(KlF + r*64 + f4);
          __builtin_nontemporal_store(v, (fv4*)(outs + (size_t)r * 25600 + f4));
        }
      }
      if (hn) {                  // write prefetched x for next token into Xl
        #pragma unroll
        for (int j = 0; j < 8; ++j) {
          int f0 = ph*32 + j*4;
          #pragma unroll
          for (int e = 0; e < 4; ++e) {
            int rw = ps*64 + f0 + e;
            Xl[rw*128 + (pc ^ ((rw & 7) << 3))] = f2bf(xr[j][e]);
          }
        }
      }
      __syncthreads();           // s0 stores done; safe to restage KlF

      // stream 1
      if (wn == 1) {
        #pragma unroll
        for (int mi = 0; mi < 2; ++mi)
          #pragma unroll
          for (int ni = 0; ni < 4; ++ni) {
            int f = ni*16 + row16;
            #pragma unroll
            for (int j = 0; j < 4; ++j)
              KlF[(m0 + mi*16 + q4*4 + j)*64 + f] = acc[mi][ni][j];
          }
      }
      __syncthreads();
      {
        float* outs = out + 13107200u + obase;
        #pragma unroll
        for (int k = 0; k < 4; ++k) {
          int s = k*512 + tid;
          int r = s >> 4, f4 = (s & 15) * 4;
          fv4 v = *(const fv4*)(KlF + r*64 + f4);
          __builtin_nontemporal_store(v, (fv4*)(outs + (size_t)r * 25600 + f4));
        }
      }
      __syncthreads();           // protect KlF (next iter phase-2 writes Kl) + Xl complete
    }

    n = nn;
  }
}

extern "C" void kernel_launch(void* const* d_in, const int* in_sizes, int n_in,
                              void* d_out, int out_size, void* d_ws, size_t ws_size,
                              hipStream_t stream)
{
  (void)in_sizes; (void)n_in; (void)out_size; (void)ws_size;
  const float* x1 = (const float*)d_in[0];
  const float* x2 = (const float*)d_in[1];
  const float* Wq = (const float*)d_in[2];
  const float* bq = (const float*)d_in[3];
  const float* pq = (const float*)d_in[4];
  const float* gq = (const float*)d_in[5];
  const float* zq = (const float*)d_in[6];
  const float* Wk = (const float*)d_in[7];
  const float* bk = (const float*)d_in[8];
  const float* pk = (const float*)d_in[9];
  const float* gk = (const float*)d_in[10];
  const float* zk = (const float*)d_in[11];
  const float* Wv = (const float*)d_in[12];
  const float* bv = (const float*)d_in[13];
  const float* pv = (const float*)d_in[14];
  const float* gv = (const float*)d_in[15];
  const float* zv = (const float*)d_in[16];
  const float* Wo = (const float*)d_in[17];
  const float* bo = (const float*)d_in[18];
  const float* po = (const float*)d_in[19];
  const float* go = (const float*)d_in[20];
  const float* zo = (const float*)d_in[21];

  unsigned short* Wb = (unsigned short*)d_ws;             // hi: 131072 B, lo: 131072 B
  unsigned*       GZ = (unsigned*)((char*)d_ws + 262144); // 131072 B

  prep_k<<<384, 256, 0, stream>>>(Wq, Wk, Wv, Wo, gq, zq, gk, zk, gv, zv, go, zo, Wb, GZ);
  fused_k<<<512, 512, 0, stream>>>(x1, x2, Wb, GZ, bq, bk, bv, bo, pq, pk, pv, po,
                                   (float*)d_out);
}

// Round 10
// 240.582 us; speedup vs baseline: 4.2658x; 4.2658x over previous
//
#include <hip/hip_runtime.h>
#include <hip/hip_bf16.h>

// MyCrossAttention fused kernel for MI355X (gfx950), round 10.
// B=4, C=128, T=400, F=64, H=4, HID=CV=32, N=B*T=1600.
// One block per n (grid=1600); 8 waves (512 thr) as 4x2 grid over [128r][128c].
// vs round 8: persistence REVERTED (r9 spilled: allocator pinned at 64 VGPR);
// LDS-staged stores REVERTED to r3's direct scattered stores (staging was
// falsified: WRITE unchanged, +60us); native bf16 converts (v_cvt_pk path);
// barriers 10 -> 6 (K+Q fused span, V-GEMM hoisted); s4v vector LDS accesses.
// Keeps: split-precision weights (W = W_hi + W_lo, 2 MFMA passes).

typedef short s8v __attribute__((ext_vector_type(8)));   // 8 bf16 bits
typedef short s4v __attribute__((ext_vector_type(4)));   // 4 bf16 bits
typedef float f4v __attribute__((ext_vector_type(4)));   // MFMA accumulator
typedef float fv4 __attribute__((ext_vector_type(4)));   // nontemporal ld

__device__ __forceinline__ unsigned short f2bf(float x){
  __hip_bfloat16 h = __float2bfloat16(x);                // RNE, HW cvt (pk-fusable)
  return __builtin_bit_cast(unsigned short, h);
}
__device__ __forceinline__ float b2f(unsigned short b){
  return __uint_as_float(((unsigned)b) << 16);
}
__device__ __forceinline__ float wred(float v){
  #pragma unroll
  for (int off = 32; off; off >>= 1) v += __shfl_xor(v, off, 64);
  return v;
}

// ---------------- prep: W -> (hi, lo) bf16 pair; (g,z) packed bf16 [r][f] ----------------
// ws layout: Wb_hi 4x16384 shorts | Wb_lo 4x16384 shorts | GZ 4x8192 u32
__global__ __launch_bounds__(256)
void prep_k(const float* __restrict__ Wq, const float* __restrict__ Wk,
            const float* __restrict__ Wv, const float* __restrict__ Wo,
            const float* __restrict__ gq, const float* __restrict__ zq,
            const float* __restrict__ gk, const float* __restrict__ zk,
            const float* __restrict__ gv, const float* __restrict__ zv,
            const float* __restrict__ go, const float* __restrict__ zo,
            unsigned short* __restrict__ Wb, unsigned* __restrict__ GZ)
{
  int t = blockIdx.x * 256 + threadIdx.x;
  if (t < 65536) {                       // 4 x [128][128] weight matrices
    int sel = t >> 14, i = t & 16383;
    const float* s = sel == 0 ? Wq : sel == 1 ? Wk : sel == 2 ? Wv : Wo;
    float w = s[i];
    unsigned short hi = f2bf(w);
    Wb[t]         = hi;
    Wb[65536 + t] = f2bf(w - b2f(hi));   // lo residue (exact regardless of rounding mode)
  } else {                               // 4 x [128][64] packed (g,z)
    int u = t - 65536;
    int sel = u >> 13, i = u & 8191;
    const float* g = sel == 0 ? gq : sel == 1 ? gk : sel == 2 ? gv : go;
    const float* z = sel == 0 ? zq : sel == 1 ? zk : sel == 2 ? zv : zo;
    GZ[u] = (unsigned)f2bf(g[i]) | ((unsigned)f2bf(z[i]) << 16);
  }
}

// ---------------- 32x64x128 GEMM tile: acc = (A_hi + A_lo) * B(LDS swizzled) ----------------
__device__ __forceinline__ void gemm_tile(const unsigned short* __restrict__ A,  // hi; lo at +65536
                                          const unsigned short* __restrict__ Bl,
                                          int m0, int n0, int row16, int q4,
                                          f4v acc[2][4])
{
  const unsigned short* Al = A + 65536;
  #pragma unroll
  for (int mi = 0; mi < 2; ++mi)
    #pragma unroll
    for (int ni = 0; ni < 4; ++ni)
      acc[mi][ni] = (f4v){0.f, 0.f, 0.f, 0.f};

  #pragma unroll
  for (int kk = 0; kk < 4; ++kk) {
    s8v ah[2], al[2];
    #pragma unroll
    for (int mi = 0; mi < 2; ++mi) {
      int off = (m0 + mi*16 + row16)*128 + kk*32 + q4*8;
      ah[mi] = *(const s8v*)(A  + off);
      al[mi] = *(const s8v*)(Al + off);
    }
    #pragma unroll
    for (int ni = 0; ni < 4; ++ni) {
      int rw = n0 + ni*16 + row16;
      const s8v b = *(const s8v*)(Bl + rw*128 + ((kk*32 + q4*8) ^ ((rw & 7) << 3)));
      #pragma unroll
      for (int mi = 0; mi < 2; ++mi) {
        acc[mi][ni] = __builtin_amdgcn_mfma_f32_16x16x32_bf16(ah[mi], b, acc[mi][ni], 0, 0, 0);
        acc[mi][ni] = __builtin_amdgcn_mfma_f32_16x16x32_bf16(al[mi], b, acc[mi][ni], 0, 0, 0);
      }
    }
  }
}

// ---------------- QKV epilogue: bias + PReLU + LN(2048 = wave tile) + g/z ----------------
__device__ __forceinline__ void qkv_epi(f4v acc[2][4],
                                        const float* __restrict__ bias,
                                        float p,
                                        const unsigned* __restrict__ GZb,  // [r][f]
                                        unsigned short* __restrict__ Lout, bool keep,
                                        int m0, int n0, int row16, int q4)
{
  float sum = 0.f, sq = 0.f;
  #pragma unroll
  for (int mi = 0; mi < 2; ++mi) {
    #pragma unroll
    for (int j = 0; j < 4; ++j) {
      float bb = bias[m0 + mi*16 + q4*4 + j];
      #pragma unroll
      for (int ni = 0; ni < 4; ++ni) {
        float v = acc[mi][ni][j] + bb;
        v = v >= 0.f ? v : p * v;
        acc[mi][ni][j] = v;
        sum += v; sq += v*v;
      }
    }
  }
  sum = wred(sum); sq = wred(sq);
  float mu = sum * (1.f/2048.f);
  float rs = rsqrtf(sq * (1.f/2048.f) - mu*mu + 1e-5f);
  #pragma unroll
  for (int mi = 0; mi < 2; ++mi) {
    int r0 = m0 + mi*16 + q4*4;
    #pragma unroll
    for (int ni = 0; ni < 4; ++ni) {
      int f   = ni*16 + row16;
      int col = n0 + f;
      int sw  = (col & 7) << 3;
      if (keep) {
        #pragma unroll
        for (int j = 0; j < 4; ++j) {
          unsigned gz = GZb[(r0 + j)*64 + f];
          float g = b2f((unsigned short)(gz & 0xffffu));
          float z = b2f((unsigned short)(gz >> 16));
          acc[mi][ni][j] = (acc[mi][ni][j] - mu) * rs * g + z;
        }
      } else {
        s4v pkv;
        #pragma unroll
        for (int j = 0; j < 4; ++j) {
          unsigned gz = GZb[(r0 + j)*64 + f];
          float g = b2f((unsigned short)(gz & 0xffffu));
          float z = b2f((unsigned short)(gz >> 16));
          pkv[j] = (short)f2bf((acc[mi][ni][j] - mu) * rs * g + z);
        }
        *(s4v*)(Lout + col*128 + (r0 ^ sw)) = pkv;   // (r0^sw)+j == (r0+j)^sw, 8B aligned
      }
    }
  }
}

// ---------------- main fused kernel ----------------
__global__ __launch_bounds__(512)
void fused_k(const float* __restrict__ x1, const float* __restrict__ x2,
             const unsigned short* __restrict__ Wb, const unsigned* __restrict__ GZ,
             const float* __restrict__ bq, const float* __restrict__ bk,
             const float* __restrict__ bv, const float* __restrict__ bo,
             const float* __restrict__ pq, const float* __restrict__ pk,
             const float* __restrict__ pv, const float* __restrict__ po,
             float* __restrict__ out)
{
  __shared__ __align__(16) unsigned short Xl[16384];  // x, [rw=s*64+f][c], swizzled
  __shared__ __align__(16) unsigned short Kl[16384];  // K -> V -> mixed O
  __shared__ float sc[16];              // raw scores [h][s][t]
  __shared__ float lnb[16];             // out-LN cross-wave partials

  const int n   = blockIdx.x;
  const int bI  = n / 400, tI = n % 400;
  const int tid = threadIdx.x;
  const int lane = tid & 63, wave = tid >> 6;
  const int wm = wave >> 1, wn = wave & 1;     // wm = head (rows), wn = stream (cols)
  const int m0 = wm * 32, n0 = wn * 64;
  const int row16 = lane & 15, q4 = lane >> 4;

  // ---- phase 1: load x -> Xl (bf16, transposed, swizzled); nontemporal loads ----
  {
    int c = tid & 127, s = (tid >> 7) & 1, half = tid >> 8;
    const float* src = (s ? x2 : x1) + ((size_t)(bI*128 + c)*400 + tI)*64 + half*32;
    #pragma unroll
    for (int j = 0; j < 8; ++j) {
      fv4 v = __builtin_nontemporal_load(((const fv4*)src) + j);
      int f0 = half*32 + j*4;
      #pragma unroll
      for (int e = 0; e < 4; ++e) {
        int rw = s*64 + f0 + e;
        Xl[rw*128 + (c ^ ((rw & 7) << 3))] = f2bf(v[e]);
      }
    }
  }
  __syncthreads();                                     // B0

  f4v acc[2][4];

  // ---- phase 2: K branch -> Kl, then Q branch (regs) — one barrier span ----
  gemm_tile(Wb + 16384*1, Xl, m0, n0, row16, q4, acc);
  qkv_epi(acc, bk, pk[wm], GZ + 8192*1, Kl, false, m0, n0, row16, q4);
  gemm_tile(Wb + 16384*0, Xl, m0, n0, row16, q4, acc);
  qkv_epi(acc, bq, pq[wm], GZ + 8192*0, Kl, true, m0, n0, row16, q4);
  __syncthreads();                                     // B1: K in Kl visible

  // ---- phase 3: scores (reads Kl), then V-GEMM (reads Xl only) ----
  {
    float p0 = 0.f, p1 = 0.f;   // scores vs K stream t=0,1 for (h=wm, s=wn)
    #pragma unroll
    for (int mi = 0; mi < 2; ++mi) {
      int r0 = m0 + mi*16 + q4*4;
      #pragma unroll
      for (int ni = 0; ni < 4; ++ni) {
        int f  = ni*16 + row16;
        int sw = (f & 7) << 3;      // (64+f)&7 == f&7
        s4v k0 = *(const s4v*)(Kl + f*128      + (r0 ^ sw));
        s4v k1 = *(const s4v*)(Kl + (64+f)*128 + (r0 ^ sw));
        #pragma unroll
        for (int j = 0; j < 4; ++j) {
          float qv = acc[mi][ni][j];
          p0 += qv * b2f((unsigned short)k0[j]);
          p1 += qv * b2f((unsigned short)k1[j]);
        }
      }
    }
    p0 = wred(p0); p1 = wred(p1);
    if (lane == 0) {
      sc[wm*4 + wn*2 + 0] = p0;
      sc[wm*4 + wn*2 + 1] = p1;
    }
  }
  gemm_tile(Wb + 16384*2, Xl, m0, n0, row16, q4, acc);  // V-GEMM: no Kl access
  __syncthreads();                                     // B2: score reads of Kl done
  qkv_epi(acc, bv, pv[wm], GZ + 8192*2, Kl, false, m0, n0, row16, q4);
  __syncthreads();                                     // B3: V in Kl visible

  // ---- phase 5: softmax + 2x2 attention mix, in place in Kl (all 512 threads) ----
  {
    const float is = 0.02209708691f;  // 1/sqrt(2048)
    #pragma unroll
    for (int i = 0; i < 2; ++i) {
      int g  = tid + 512*i;           // 1024 groups: [f in 64][cgroup in 16]
      int f  = g >> 4, cg = g & 15, c0 = cg*8, h = cg >> 2;
      float s00 = sc[h*4+0]*is, s01 = sc[h*4+1]*is;
      float s10 = sc[h*4+2]*is, s11 = sc[h*4+3]*is;
      float mA = fmaxf(s00, s01), e0 = __expf(s00-mA), e1 = __expf(s01-mA);
      float a00 = e0/(e0+e1), a01 = e1/(e0+e1);
      float mB = fmaxf(s10, s11), e2 = __expf(s10-mB), e3 = __expf(s11-mB);
      float a10 = e2/(e2+e3), a11 = e3/(e2+e3);
      int sw = (f & 7) << 3;
      int off0 = f*128      + (c0 ^ sw);
      int off1 = (64+f)*128 + (c0 ^ sw);
      s8v v0 = *(const s8v*)(Kl + off0);
      s8v v1 = *(const s8v*)(Kl + off1);
      s8v o0, o1;
      #pragma unroll
      for (int e = 0; e < 8; ++e) {
        float x0  = b2f((unsigned short)v0[e]);
        float x1v = b2f((unsigned short)v1[e]);
        o0[e] = (short)f2bf(a00*x0 + a01*x1v);
        o1[e] = (short)f2bf(a10*x0 + a11*x1v);
      }
      *(s8v*)(Kl + off0) = o0;
      *(s8v*)(Kl + off1) = o1;
    }
  }
  __syncthreads();                                     // B4: mixed O visible

  // ---- phase 6: output projection + LN(8192 per stream) + g/z + residual + store ----
  gemm_tile(Wb + 16384*3, Kl, m0, n0, row16, q4, acc);
  {
    float pov = po[0];
    float sum = 0.f, sq = 0.f;
    #pragma unroll
    for (int mi = 0; mi < 2; ++mi) {
      #pragma unroll
      for (int j = 0; j < 4; ++j) {
        float bb = bo[m0 + mi*16 + q4*4 + j];
        #pragma unroll
        for (int ni = 0; ni < 4; ++ni) {
          float v = acc[mi][ni][j] + bb;
          v = v >= 0.f ? v : pov * v;
          acc[mi][ni][j] = v;
          sum += v; sq += v*v;
        }
      }
    }
    sum = wred(sum); sq = wred(sq);
    if (lane == 0) { lnb[wave] = sum; lnb[8 + wave] = sq; }
    __syncthreads();                                   // B5
    float tot  = lnb[wn]   + lnb[wn+2]   + lnb[wn+4]   + lnb[wn+6];
    float totq = lnb[8+wn] + lnb[8+wn+2] + lnb[8+wn+4] + lnb[8+wn+6];
    float mu = tot * (1.f/8192.f);
    float rs = rsqrtf(totq * (1.f/8192.f) - mu*mu + 1e-5f);
    const unsigned* GZo = GZ + 8192*3;
    float* outs = out + (size_t)wn * 13107200u;  // s = wn selects y1/y2
    #pragma unroll
    for (int mi = 0; mi < 2; ++mi) {
      int r0 = m0 + mi*16 + q4*4;
      #pragma unroll
      for (int ni = 0; ni < 4; ++ni) {
        int f   = ni*16 + row16;
        int col = n0 + f;
        int sw  = (col & 7) << 3;
        s4v xv = *(const s4v*)(Xl + col*128 + (r0 ^ sw));  // residual (bf16-rounded x)
        #pragma unroll
        for (int j = 0; j < 4; ++j) {
          int r = r0 + j;
          unsigned gz = GZo[r*64 + f];
          float g = b2f((unsigned short)(gz & 0xffffu));
          float z = b2f((unsigned short)(gz >> 16));
          float y = (acc[mi][ni][j] - mu) * rs * g + z;
          outs[((size_t)(bI*128 + r)*400 + tI)*64 + f] = y + b2f((unsigned short)xv[j]);
        }
      }
    }
  }
}

extern "C" void kernel_launch(void* const* d_in, const int* in_sizes, int n_in,
                              void* d_out, int out_size, void* d_ws, size_t ws_size,
                              hipStream_t stream)
{
  (void)in_sizes; (void)n_in; (void)out_size; (void)ws_size;
  const float* x1 = (const float*)d_in[0];
  const float* x2 = (const float*)d_in[1];
  const float* Wq = (const float*)d_in[2];
  const float* bq = (const float*)d_in[3];
  const float* pq = (const float*)d_in[4];
  const float* gq = (const float*)d_in[5];
  const float* zq = (const float*)d_in[6];
  const float* Wk = (const float*)d_in[7];
  const float* bk = (const float*)d_in[8];
  const float* pk = (const float*)d_in[9];
  const float* gk = (const float*)d_in[10];
  const float* zk = (const float*)d_in[11];
  const float* Wv = (const float*)d_in[12];
  const float* bv = (const float*)d_in[13];
  const float* pv = (const float*)d_in[14];
  const float* gv = (const float*)d_in[15];
  const float* zv = (const float*)d_in[16];
  const float* Wo = (const float*)d_in[17];
  const float* bo = (const float*)d_in[18];
  const float* po = (const float*)d_in[19];
  const float* go = (const float*)d_in[20];
  const float* zo = (const float*)d_in[21];

  unsigned short* Wb = (unsigned short*)d_ws;             // hi: 131072 B, lo: 131072 B
  unsigned*       GZ = (unsigned*)((char*)d_ws + 262144); // 131072 B

  prep_k<<<384, 256, 0, stream>>>(Wq, Wk, Wv, Wo, gq, zq, gk, zk, gv, zv, go, zo, Wb, GZ);
  fused_k<<<1600, 512, 0, stream>>>(x1, x2, Wb, GZ, bq, bk, bv, bo, pq, pk, pv, po,
                                    (float*)d_out);
}